// Round 7
// baseline (586.405 us; speedup 1.0000x reference)
//
#include <hip/hip_runtime.h>
#include <cmath>

// ---------------------------------------------------------------------------
// Decoder_1898375544952: STGCN decoder (CSR gather + register-blocked GEMM)
//   h0 = x @ W_lin + b_lin                         [N,16]
//   h3 = relu(h0 @ Ws3 + mean_agg(h0) @ Wn3 + b3)  [N,32]
//   h2 = relu(h3 @ Ws2 + mean_agg(h3) @ Wn2 + b2)  [N,64]
//   out= sigm(h2 @ Ws1 + mean_agg(h2) @ Wn1 + b1)  [N,128]
//
// R1: fp32 atomic scatter = 2 GB HBM write-through -> CSR gather (4.7x).
// R2: combine kernels LDS-BW bound -> register-blocked GEMM.
// R3: over-unrolled GEMM spilled (VGPR=256) -> unroll-1 chunks, TMx4 tiles.
// R4: fill = atomic+dependent-random-store -> rank from hist atomicAdd.
// R5/R6: gather is NOT latency-bound (8x MLP neutral) -> it is address-
//   divergence request-rate bound (64 distinct lines per wave-load; 33.5M
//   line-requests for C=64) -> R7: wave-per-node coalesced gather. Lane ->
//   (neighbor-slot l/C, channel l%C): each load reads 64/C complete rows
//   contiguously (2-4 lines/instr instead of 64); shfl-reduce across slots.
// ---------------------------------------------------------------------------

__global__ void hist_rank_kernel(const int* __restrict__ dst, int* __restrict__ cnt,
                                 int* __restrict__ rank, int E) {
    int i = blockIdx.x * blockDim.x + threadIdx.x;
    if (i >= E) return;
    rank[i] = atomicAdd(&cnt[dst[i]], 1);
}

// Block-level exclusive scan of cnt -> row_ptr (partial), block sums -> bsum.
// Requires N % 256 == 0.
__global__ void scan1_kernel(const int* __restrict__ cnt, int* __restrict__ row_ptr,
                             int* __restrict__ bsum) {
    __shared__ int s[256];
    int i = blockIdx.x * 256 + threadIdx.x;
    int v = cnt[i];
    s[threadIdx.x] = v;
    __syncthreads();
    for (int off = 1; off < 256; off <<= 1) {
        int t = (threadIdx.x >= off) ? s[threadIdx.x - off] : 0;
        __syncthreads();
        s[threadIdx.x] += t;
        __syncthreads();
    }
    row_ptr[i] = s[threadIdx.x] - v;   // exclusive within block
    if (threadIdx.x == 255) bsum[blockIdx.x] = s[255];
}

// Exclusive scan of bsum[NB] in place, single block of NB threads (NB<=1024).
__global__ void scan2_kernel(int* __restrict__ bsum, int NB) {
    extern __shared__ int s2[];
    int v = (threadIdx.x < NB) ? bsum[threadIdx.x] : 0;
    s2[threadIdx.x] = v;
    __syncthreads();
    for (int off = 1; off < NB; off <<= 1) {
        int t = (threadIdx.x >= off) ? s2[threadIdx.x - off] : 0;
        __syncthreads();
        s2[threadIdx.x] += t;
        __syncthreads();
    }
    if (threadIdx.x < NB) bsum[threadIdx.x] = s2[threadIdx.x] - v;
}

__global__ void scan3_kernel(int* __restrict__ row_ptr, const int* __restrict__ bsum,
                             int N, int E) {
    int i = blockIdx.x * 256 + threadIdx.x;
    row_ptr[i] += bsum[blockIdx.x];
    if (i == 0) row_ptr[N] = E;
}

// Atomic-free CSR fill: position comes from precomputed rank.
__global__ void fill_kernel(const int* __restrict__ src, const int* __restrict__ dst,
                            const int* __restrict__ row_ptr, const int* __restrict__ rank,
                            int* __restrict__ csr_src, int E) {
    int i = blockIdx.x * blockDim.x + threadIdx.x;
    if (i >= E) return;
    csr_src[row_ptr[dst[i]] + rank[i]] = src[i];
}

__global__ void lin16_kernel(const float* __restrict__ x, const float* __restrict__ W,
                             const float* __restrict__ b, float* __restrict__ h, int N) {
    __shared__ float sW[256];
    __shared__ float sb[16];
    sW[threadIdx.x] = W[threadIdx.x];          // blockDim.x == 256
    if (threadIdx.x < 16) sb[threadIdx.x] = b[threadIdx.x];
    __syncthreads();
    int n = blockIdx.x * blockDim.x + threadIdx.x;
    if (n >= N) return;
    const float4* xr = (const float4*)(x + (size_t)n * 16);
    float4 x0 = xr[0], x1 = xr[1], x2 = xr[2], x3 = xr[3];
    float xi[16] = {x0.x, x0.y, x0.z, x0.w, x1.x, x1.y, x1.z, x1.w,
                    x2.x, x2.y, x2.z, x2.w, x3.x, x3.y, x3.z, x3.w};
    float o[16];
#pragma unroll
    for (int j = 0; j < 16; j++) o[j] = sb[j];
#pragma unroll
    for (int k = 0; k < 16; k++) {
        float xv = xi[k];
#pragma unroll
        for (int j = 0; j < 16; j++) o[j] += xv * sW[k * 16 + j];
    }
    float4* hr = (float4*)(h + (size_t)n * 16);
    hr[0] = make_float4(o[0], o[1], o[2], o[3]);
    hr[1] = make_float4(o[4], o[5], o[6], o[7]);
    hr[2] = make_float4(o[8], o[9], o[10], o[11]);
    hr[3] = make_float4(o[12], o[13], o[14], o[15]);
}

// Wave-per-node coalesced gather:
//   agg[n][c] = (1/max(deg,1)) * sum_j h[csr_src[j]][c]
// One 64-lane wave per node. lane -> (slot = lane/C, channel = lane%C);
// each load instruction reads 64/C complete C-float rows contiguously.
// Cross-slot reduce via shfl_down; lanes < C store the result.
template <int C>
__global__ void gather_kernel(const int* __restrict__ row_ptr, const int* __restrict__ csr_src,
                              const float* __restrict__ h, float* __restrict__ agg, int N) {
    constexpr int NPW = 64 / C;                       // neighbor slots per wave
    const int wave = (blockIdx.x * blockDim.x + threadIdx.x) >> 6;
    if (wave >= N) return;
    const int lane = threadIdx.x & 63;
    const int c    = lane & (C - 1);
    const int sub  = lane / C;
    const int n    = wave;
    const int beg  = row_ptr[n];
    const int end  = row_ptr[n + 1];

    float s0 = 0.f, s1 = 0.f;
    int j = beg + sub;
    for (; j + NPW < end; j += 2 * NPW) {
        int a = csr_src[j];
        int b = csr_src[j + NPW];
        s0 += h[(size_t)a * C + c];
        s1 += h[(size_t)b * C + c];
    }
    if (j < end) {
        int a = csr_src[j];
        s0 += h[(size_t)a * C + c];
    }
    float s = s0 + s1;

    // reduce across neighbor slots (lanes c, c+C, c+2C, ...)
#pragma unroll
    for (int off = C; off < 64; off <<= 1)
        s += __shfl_down(s, off, 64);

    if (lane < C) {
        float inv = 1.0f / fmaxf((float)(end - beg), 1.0f);
        agg[(size_t)n * C + lane] = s * inv;
    }
}

// Register-blocked GEMM: out = act([h | a] @ [Ws; Wn] + b). 256 threads.
// Thread owns TM interleaved rows (m = ty + TY*r) x TN=4 cols; As m-major.
// ACT: 0 = relu, 1 = sigmoid
template <int CI, int NOUT, int TM, int TN, int ACT>
__global__ __launch_bounds__(256) void gemm_kernel(
    const float* __restrict__ hbuf,   // [N][CI]
    const float* __restrict__ abuf,   // [N][CI]  (already divided by deg)
    const float* __restrict__ Ws,     // [CI][NOUT]
    const float* __restrict__ Wn,     // [CI][NOUT]
    const float* __restrict__ bias,   // [NOUT]
    float* __restrict__ out, int N)
{
    constexpr int K   = 2 * CI;
    constexpr int BK  = (CI < 32) ? CI : 32;   // each chunk entirely in h- or a-half
    constexpr int KQ  = BK / 4;
    constexpr int TX  = NOUT / TN;
    constexpr int TY  = 256 / TX;
    constexpr int BM  = TY * TM;
    constexpr int LDA = BK + 4;                // multiple of 4 -> float4-aligned rows
    __shared__ float As[BM][LDA];
    __shared__ float Bs[BK][NOUT];

    const int tid  = threadIdx.x;
    const int tx   = tid % TX;
    const int ty   = tid / TX;
    const int row0 = blockIdx.x * BM;
    const int j0   = tx * TN;

    float acc[TM][TN];
#pragma unroll
    for (int r = 0; r < TM; r++)
#pragma unroll
        for (int j = 0; j < TN; j++) acc[r][j] = 0.0f;

#pragma unroll 1
    for (int k0 = 0; k0 < K; k0 += BK) {
        const float* Asrc;
        const float* Bsrc;
        int ks;
        if (k0 < CI) { Asrc = hbuf; Bsrc = Ws; ks = k0; }
        else         { Asrc = abuf; Bsrc = Wn; ks = k0 - CI; }

        for (int idx = tid; idx < BM * KQ; idx += 256) {
            int m  = idx / KQ;
            int kq = idx - m * KQ;
            float4 v = *(const float4*)(Asrc + (size_t)(row0 + m) * CI + ks + kq * 4);
            *(float4*)&As[m][kq * 4] = v;
        }
        for (int idx = tid; idx < BK * (NOUT / 4); idx += 256) {
            int kk = idx / (NOUT / 4);
            int jq = idx - kk * (NOUT / 4);
            *(float4*)&Bs[kk][jq * 4] =
                *(const float4*)(Bsrc + (size_t)(ks + kk) * NOUT + jq * 4);
        }
        __syncthreads();

#pragma unroll 8
        for (int k = 0; k < BK; k++) {
            float4 bv = *(const float4*)&Bs[k][j0];
            float a[TM];
#pragma unroll
            for (int r = 0; r < TM; r++) a[r] = As[ty + TY * r][k];
#pragma unroll
            for (int r = 0; r < TM; r++) {
                acc[r][0] += a[r] * bv.x;
                acc[r][1] += a[r] * bv.y;
                acc[r][2] += a[r] * bv.z;
                acc[r][3] += a[r] * bv.w;
            }
        }
        __syncthreads();
    }

    float4 bb = *(const float4*)(bias + j0);
#pragma unroll
    for (int r = 0; r < TM; r++) {
        size_t nrow = (size_t)(row0 + ty + TY * r);
        float4 v;
        v.x = acc[r][0] + bb.x;
        v.y = acc[r][1] + bb.y;
        v.z = acc[r][2] + bb.z;
        v.w = acc[r][3] + bb.w;
        if (ACT == 0) {
            v.x = fmaxf(v.x, 0.0f); v.y = fmaxf(v.y, 0.0f);
            v.z = fmaxf(v.z, 0.0f); v.w = fmaxf(v.w, 0.0f);
        } else {
            v.x = 1.0f / (1.0f + __expf(-v.x));
            v.y = 1.0f / (1.0f + __expf(-v.y));
            v.z = 1.0f / (1.0f + __expf(-v.z));
            v.w = 1.0f / (1.0f + __expf(-v.w));
        }
        *(float4*)(out + nrow * NOUT + j0) = v;
    }
}

extern "C" void kernel_launch(void* const* d_in, const int* in_sizes, int n_in,
                              void* d_out, int out_size, void* d_ws, size_t ws_size,
                              hipStream_t stream) {
    const float* x     = (const float*)d_in[0];
    const int*   ei    = (const int*)d_in[1];
    // d_in[2]: batch (unused)
    const float* W_lin = (const float*)d_in[3];
    const float* b_lin = (const float*)d_in[4];
    const float* Ws3   = (const float*)d_in[5];
    const float* Wn3   = (const float*)d_in[6];
    const float* b3    = (const float*)d_in[7];
    const float* Ws2   = (const float*)d_in[8];
    const float* Wn2   = (const float*)d_in[9];
    const float* b2    = (const float*)d_in[10];
    const float* Ws1   = (const float*)d_in[11];
    const float* Wn1   = (const float*)d_in[12];
    const float* b1    = (const float*)d_in[13];
    float* out = (float*)d_out;

    const int N = in_sizes[0] / 16;
    const int E = in_sizes[1] / 2;
    const int* src = ei;
    const int* dst = ei + E;
    const int NB = (N + 255) / 256;   // scan blocks (512 for N=131072)

    // Workspace (4 B elems). Peak = 76.55 MB (same aliasing as R2-R6, proven fit).
    //   row_ptr : [0, N+1)
    //   cnt     : [N+1, 2N+1)
    //   bsum    : [2N+1, 2N+1+NB)
    //   csr_src : [A, A+E)
    //   regionA (64N floats): h0 [0,16N) agg16 [16N,32N); later h2 [0,64N)
    //   regionB (64N floats): rank [0,E) during CSR build (dead before h3);
    //                         h3 [0,32N) agg32 [32N,64N); later agg64 [0,64N)
    int* wsi = (int*)d_ws;
    int* row_ptr = wsi;
    int* cnt     = wsi + (N + 1);
    int* bsum    = wsi + (2 * N + 1);
    size_t A = (size_t)(2 * N + 1 + NB + 3) & ~(size_t)3;
    int* csr_src = wsi + A;
    size_t P0 = (A + (size_t)E + 3) & ~(size_t)3;
    float* regA = (float*)(wsi + P0);
    float* regB = regA + (size_t)64 * N;

    float* h0    = regA;
    float* agg16 = regA + (size_t)16 * N;
    float* h2    = regA;                      // after h0/agg16 dead
    int*   rank  = (int*)regB;                // CSR-build only (E <= 32N ints)
    float* h3    = regB;
    float* agg32 = regB + (size_t)32 * N;
    float* agg64 = regB;                      // after h3/agg32 dead

    const int BLK = 256;

    // ---- CSR build: hist computes rank; fill is atomic-free ----
    hipMemsetAsync(cnt, 0, (size_t)N * 4, stream);
    hist_rank_kernel<<<(E + BLK - 1) / BLK, BLK, 0, stream>>>(dst, cnt, rank, E);
    scan1_kernel<<<NB, 256, 0, stream>>>(cnt, row_ptr, bsum);
    scan2_kernel<<<1, NB, NB * sizeof(int), stream>>>(bsum, NB);
    scan3_kernel<<<NB, 256, 0, stream>>>(row_ptr, bsum, N, E);
    fill_kernel<<<(E + BLK - 1) / BLK, BLK, 0, stream>>>(src, dst, row_ptr, rank, csr_src, E);

    // ---- h0 = x @ W_lin + b_lin ----
    lin16_kernel<<<(N + BLK - 1) / BLK, BLK, 0, stream>>>(x, W_lin, b_lin, h0, N);

    // ---- block3: 16 -> 32, relu ----  (gather: 1 wave/node, 4 waves/block)
    gather_kernel<16><<<(N + 3) / 4, 256, 0, stream>>>(row_ptr, csr_src, h0, agg16, N);
    gemm_kernel<16, 32, 4, 4, 0><<<N / 128, 256, 0, stream>>>(h0, agg16, Ws3, Wn3, b3, h3, N);

    // ---- block2: 32 -> 64, relu ----
    gather_kernel<32><<<(N + 3) / 4, 256, 0, stream>>>(row_ptr, csr_src, h3, agg32, N);
    gemm_kernel<32, 64, 8, 4, 0><<<N / 128, 256, 0, stream>>>(h3, agg32, Ws2, Wn2, b2, h2, N);

    // ---- block1: 64 -> 128, sigmoid -> d_out ----
    gather_kernel<64><<<(N + 3) / 4, 256, 0, stream>>>(row_ptr, csr_src, h2, agg64, N);
    gemm_kernel<64, 128, 8, 4, 1><<<N / 64, 256, 0, stream>>>(h2, agg64, Ws1, Wn1, b1, out, N);
}

// Round 8
// 444.179 us; speedup vs baseline: 1.3202x; 1.3202x over previous
//
#include <hip/hip_runtime.h>
#include <cmath>

// ---------------------------------------------------------------------------
// Decoder_1898375544952: STGCN decoder (CSR gather + register-blocked GEMM)
//   h0 = x @ W_lin + b_lin                         [N,16]
//   h3 = relu(h0 @ Ws3 + mean_agg(h0) @ Wn3 + b3)  [N,32]
//   h2 = relu(h3 @ Ws2 + mean_agg(h3) @ Wn2 + b2)  [N,64]
//   out= sigm(h2 @ Ws1 + mean_agg(h2) @ Wn1 + b1)  [N,128]
//
// R1: fp32 atomic scatter = 2 GB HBM write-through -> CSR gather (4.7x).
// R2: combine kernels LDS-BW bound -> register-blocked GEMM.
// R3: over-unrolled GEMM spilled (VGPR=256) -> unroll-1 chunks, TMx4 tiles.
// R4: fill = atomic+dependent-random-store -> rank from hist atomicAdd.
// R5/R6/R7: gather is neither latency- nor request-rate-bound; it is BYTE-
//   bound on L2-miss fabric (~352 MB @ ~3.3 TB/s; h2=33.5MB >> 4MB L2/XCD).
//   R7's 4B/lane "coalesced" layout regressed (VALU overhead/bytes-in-flight).
// R8: store h/agg tables in fp16 (fp32 accumulate, half storage) -> fabric
//   bytes halve. Gather back to R6 layout: 16B/lane = 8 channels/thread.
// ---------------------------------------------------------------------------

typedef __attribute__((ext_vector_type(8))) _Float16 half8;

__global__ void hist_rank_kernel(const int* __restrict__ dst, int* __restrict__ cnt,
                                 int* __restrict__ rank, int E) {
    int i = blockIdx.x * blockDim.x + threadIdx.x;
    if (i >= E) return;
    rank[i] = atomicAdd(&cnt[dst[i]], 1);
}

// Block-level exclusive scan of cnt -> row_ptr (partial), block sums -> bsum.
// Requires N % 256 == 0.
__global__ void scan1_kernel(const int* __restrict__ cnt, int* __restrict__ row_ptr,
                             int* __restrict__ bsum) {
    __shared__ int s[256];
    int i = blockIdx.x * 256 + threadIdx.x;
    int v = cnt[i];
    s[threadIdx.x] = v;
    __syncthreads();
    for (int off = 1; off < 256; off <<= 1) {
        int t = (threadIdx.x >= off) ? s[threadIdx.x - off] : 0;
        __syncthreads();
        s[threadIdx.x] += t;
        __syncthreads();
    }
    row_ptr[i] = s[threadIdx.x] - v;   // exclusive within block
    if (threadIdx.x == 255) bsum[blockIdx.x] = s[255];
}

// Exclusive scan of bsum[NB] in place, single block of NB threads (NB<=1024).
__global__ void scan2_kernel(int* __restrict__ bsum, int NB) {
    extern __shared__ int s2[];
    int v = (threadIdx.x < NB) ? bsum[threadIdx.x] : 0;
    s2[threadIdx.x] = v;
    __syncthreads();
    for (int off = 1; off < NB; off <<= 1) {
        int t = (threadIdx.x >= off) ? s2[threadIdx.x - off] : 0;
        __syncthreads();
        s2[threadIdx.x] += t;
        __syncthreads();
    }
    if (threadIdx.x < NB) bsum[threadIdx.x] = s2[threadIdx.x] - v;
}

__global__ void scan3_kernel(int* __restrict__ row_ptr, const int* __restrict__ bsum,
                             int N, int E) {
    int i = blockIdx.x * 256 + threadIdx.x;
    row_ptr[i] += bsum[blockIdx.x];
    if (i == 0) row_ptr[N] = E;
}

// Atomic-free CSR fill: position comes from precomputed rank.
__global__ void fill_kernel(const int* __restrict__ src, const int* __restrict__ dst,
                            const int* __restrict__ row_ptr, const int* __restrict__ rank,
                            int* __restrict__ csr_src, int E) {
    int i = blockIdx.x * blockDim.x + threadIdx.x;
    if (i >= E) return;
    csr_src[row_ptr[dst[i]] + rank[i]] = src[i];
}

// h0 = x @ W (16x16) + b, stored fp16
__global__ void lin16_kernel(const float* __restrict__ x, const float* __restrict__ W,
                             const float* __restrict__ b, _Float16* __restrict__ h, int N) {
    __shared__ float sW[256];
    __shared__ float sb[16];
    sW[threadIdx.x] = W[threadIdx.x];          // blockDim.x == 256
    if (threadIdx.x < 16) sb[threadIdx.x] = b[threadIdx.x];
    __syncthreads();
    int n = blockIdx.x * blockDim.x + threadIdx.x;
    if (n >= N) return;
    const float4* xr = (const float4*)(x + (size_t)n * 16);
    float4 x0 = xr[0], x1 = xr[1], x2 = xr[2], x3 = xr[3];
    float xi[16] = {x0.x, x0.y, x0.z, x0.w, x1.x, x1.y, x1.z, x1.w,
                    x2.x, x2.y, x2.z, x2.w, x3.x, x3.y, x3.z, x3.w};
    float o[16];
#pragma unroll
    for (int j = 0; j < 16; j++) o[j] = sb[j];
#pragma unroll
    for (int k = 0; k < 16; k++) {
        float xv = xi[k];
#pragma unroll
        for (int j = 0; j < 16; j++) o[j] += xv * sW[k * 16 + j];
    }
    half8 h0v, h1v;
#pragma unroll
    for (int j = 0; j < 8; j++) { h0v[j] = (_Float16)o[j]; h1v[j] = (_Float16)o[j + 8]; }
    half8* hr = (half8*)(h + (size_t)n * 16);
    hr[0] = h0v;
    hr[1] = h1v;
}

// agg[n][g*8..] = (1/max(deg,1)) * sum over CSR neighbors of h[src][g*8..]
// fp16 storage, fp32 accumulate; 16 B/lane loads (8 channels per thread);
// 4-way unrolled neighbor loop.
template <int C>
__global__ void gather_kernel(const int* __restrict__ row_ptr, const int* __restrict__ csr_src,
                              const _Float16* __restrict__ h, _Float16* __restrict__ agg, int N) {
    constexpr int GP = C / 8;
    int t = blockIdx.x * blockDim.x + threadIdx.x;
    int total = N * GP;
    if (t >= total) return;
    int n = t / GP;
    int g = t - n * GP;
    const int beg = row_ptr[n];
    const int end = row_ptr[n + 1];
    const size_t goff = (size_t)g * 8;

    float a0[8], a1[8];
#pragma unroll
    for (int i = 0; i < 8; i++) { a0[i] = 0.f; a1[i] = 0.f; }

    int j = beg;
    for (; j + 4 <= end; j += 4) {
        int i0 = csr_src[j + 0], i1 = csr_src[j + 1], i2 = csr_src[j + 2], i3 = csr_src[j + 3];
        half8 v0 = *(const half8*)(h + (size_t)i0 * C + goff);
        half8 v1 = *(const half8*)(h + (size_t)i1 * C + goff);
        half8 v2 = *(const half8*)(h + (size_t)i2 * C + goff);
        half8 v3 = *(const half8*)(h + (size_t)i3 * C + goff);
#pragma unroll
        for (int i = 0; i < 8; i++) {
            a0[i] += (float)v0[i] + (float)v2[i];
            a1[i] += (float)v1[i] + (float)v3[i];
        }
    }
    for (; j < end; ++j) {
        int i0 = csr_src[j];
        half8 v0 = *(const half8*)(h + (size_t)i0 * C + goff);
#pragma unroll
        for (int i = 0; i < 8; i++) a0[i] += (float)v0[i];
    }

    float inv = 1.0f / fmaxf((float)(end - beg), 1.0f);
    half8 r;
#pragma unroll
    for (int i = 0; i < 8; i++) r[i] = (_Float16)((a0[i] + a1[i]) * inv);
    *(half8*)(agg + (size_t)n * C + goff) = r;
}

// Register-blocked GEMM: out = act([h | a] @ [Ws; Wn] + b). 256 threads.
// A tables are fp16 (converted to fp32 during LDS staging); B/bias/out fp32.
// Thread owns TM interleaved rows (m = ty + TY*r) x TN=4 cols; As m-major.
// ACT: 0 = relu, 1 = sigmoid
template <int CI, int NOUT, int TM, int TN, int ACT>
__global__ __launch_bounds__(256) void gemm_kernel(
    const _Float16* __restrict__ hbuf, // [N][CI]
    const _Float16* __restrict__ abuf, // [N][CI]  (already divided by deg)
    const float* __restrict__ Ws,      // [CI][NOUT]
    const float* __restrict__ Wn,      // [CI][NOUT]
    const float* __restrict__ bias,    // [NOUT]
    float* __restrict__ out, int N)
{
    constexpr int K   = 2 * CI;
    constexpr int BK  = (CI < 32) ? CI : 32;   // each chunk entirely in h- or a-half
    constexpr int KQ8 = BK / 8;
    constexpr int TX  = NOUT / TN;
    constexpr int TY  = 256 / TX;
    constexpr int BM  = TY * TM;
    constexpr int LDA = BK + 8;                // rows 16B-aligned (LDA*4 % 16 == 0)
    __shared__ float As[BM][LDA];
    __shared__ float Bs[BK][NOUT];

    const int tid  = threadIdx.x;
    const int tx   = tid % TX;
    const int ty   = tid / TX;
    const int row0 = blockIdx.x * BM;
    const int j0   = tx * TN;

    float acc[TM][TN];
#pragma unroll
    for (int r = 0; r < TM; r++)
#pragma unroll
        for (int j = 0; j < TN; j++) acc[r][j] = 0.0f;

#pragma unroll 1
    for (int k0 = 0; k0 < K; k0 += BK) {
        const _Float16* Asrc;
        const float* Bsrc;
        int ks;
        if (k0 < CI) { Asrc = hbuf; Bsrc = Ws; ks = k0; }
        else         { Asrc = abuf; Bsrc = Wn; ks = k0 - CI; }

        // stage A: fp16 -> fp32, 16 B (8 halves) per load
        for (int idx = tid; idx < BM * KQ8; idx += 256) {
            int m  = idx / KQ8;
            int kq = idx - m * KQ8;
            half8 v = *(const half8*)(Asrc + (size_t)(row0 + m) * CI + ks + kq * 8);
            float4 f0, f1;
            f0.x = (float)v[0]; f0.y = (float)v[1]; f0.z = (float)v[2]; f0.w = (float)v[3];
            f1.x = (float)v[4]; f1.y = (float)v[5]; f1.z = (float)v[6]; f1.w = (float)v[7];
            *(float4*)&As[m][kq * 8]     = f0;
            *(float4*)&As[m][kq * 8 + 4] = f1;
        }
        // stage B: fp32 weights
        for (int idx = tid; idx < BK * (NOUT / 4); idx += 256) {
            int kk = idx / (NOUT / 4);
            int jq = idx - kk * (NOUT / 4);
            *(float4*)&Bs[kk][jq * 4] =
                *(const float4*)(Bsrc + (size_t)(ks + kk) * NOUT + jq * 4);
        }
        __syncthreads();

#pragma unroll 8
        for (int k = 0; k < BK; k++) {
            float4 bv = *(const float4*)&Bs[k][j0];
            float a[TM];
#pragma unroll
            for (int r = 0; r < TM; r++) a[r] = As[ty + TY * r][k];
#pragma unroll
            for (int r = 0; r < TM; r++) {
                acc[r][0] += a[r] * bv.x;
                acc[r][1] += a[r] * bv.y;
                acc[r][2] += a[r] * bv.z;
                acc[r][3] += a[r] * bv.w;
            }
        }
        __syncthreads();
    }

    float4 bb = *(const float4*)(bias + j0);
#pragma unroll
    for (int r = 0; r < TM; r++) {
        size_t nrow = (size_t)(row0 + ty + TY * r);
        float4 v;
        v.x = acc[r][0] + bb.x;
        v.y = acc[r][1] + bb.y;
        v.z = acc[r][2] + bb.z;
        v.w = acc[r][3] + bb.w;
        if (ACT == 0) {
            v.x = fmaxf(v.x, 0.0f); v.y = fmaxf(v.y, 0.0f);
            v.z = fmaxf(v.z, 0.0f); v.w = fmaxf(v.w, 0.0f);
        } else {
            v.x = 1.0f / (1.0f + __expf(-v.x));
            v.y = 1.0f / (1.0f + __expf(-v.y));
            v.z = 1.0f / (1.0f + __expf(-v.z));
            v.w = 1.0f / (1.0f + __expf(-v.w));
        }
        *(float4*)(out + nrow * NOUT + j0) = v;
    }
}

// Variant writing fp16 output (for intermediate layers h3, h2).
template <int CI, int NOUT, int TM, int TN, int ACT>
__global__ __launch_bounds__(256) void gemm_h_kernel(
    const _Float16* __restrict__ hbuf,
    const _Float16* __restrict__ abuf,
    const float* __restrict__ Ws,
    const float* __restrict__ Wn,
    const float* __restrict__ bias,
    _Float16* __restrict__ out, int N)
{
    constexpr int K   = 2 * CI;
    constexpr int BK  = (CI < 32) ? CI : 32;
    constexpr int KQ8 = BK / 8;
    constexpr int TX  = NOUT / TN;
    constexpr int TY  = 256 / TX;
    constexpr int BM  = TY * TM;
    constexpr int LDA = BK + 8;
    __shared__ float As[BM][LDA];
    __shared__ float Bs[BK][NOUT];

    const int tid  = threadIdx.x;
    const int tx   = tid % TX;
    const int ty   = tid / TX;
    const int row0 = blockIdx.x * BM;
    const int j0   = tx * TN;

    float acc[TM][TN];
#pragma unroll
    for (int r = 0; r < TM; r++)
#pragma unroll
        for (int j = 0; j < TN; j++) acc[r][j] = 0.0f;

#pragma unroll 1
    for (int k0 = 0; k0 < K; k0 += BK) {
        const _Float16* Asrc;
        const float* Bsrc;
        int ks;
        if (k0 < CI) { Asrc = hbuf; Bsrc = Ws; ks = k0; }
        else         { Asrc = abuf; Bsrc = Wn; ks = k0 - CI; }

        for (int idx = tid; idx < BM * KQ8; idx += 256) {
            int m  = idx / KQ8;
            int kq = idx - m * KQ8;
            half8 v = *(const half8*)(Asrc + (size_t)(row0 + m) * CI + ks + kq * 8);
            float4 f0, f1;
            f0.x = (float)v[0]; f0.y = (float)v[1]; f0.z = (float)v[2]; f0.w = (float)v[3];
            f1.x = (float)v[4]; f1.y = (float)v[5]; f1.z = (float)v[6]; f1.w = (float)v[7];
            *(float4*)&As[m][kq * 8]     = f0;
            *(float4*)&As[m][kq * 8 + 4] = f1;
        }
        for (int idx = tid; idx < BK * (NOUT / 4); idx += 256) {
            int kk = idx / (NOUT / 4);
            int jq = idx - kk * (NOUT / 4);
            *(float4*)&Bs[kk][jq * 4] =
                *(const float4*)(Bsrc + (size_t)(ks + kk) * NOUT + jq * 4);
        }
        __syncthreads();

#pragma unroll 8
        for (int k = 0; k < BK; k++) {
            float4 bv = *(const float4*)&Bs[k][j0];
            float a[TM];
#pragma unroll
            for (int r = 0; r < TM; r++) a[r] = As[ty + TY * r][k];
#pragma unroll
            for (int r = 0; r < TM; r++) {
                acc[r][0] += a[r] * bv.x;
                acc[r][1] += a[r] * bv.y;
                acc[r][2] += a[r] * bv.z;
                acc[r][3] += a[r] * bv.w;
            }
        }
        __syncthreads();
    }

    float4 bb = *(const float4*)(bias + j0);
#pragma unroll
    for (int r = 0; r < TM; r++) {
        size_t nrow = (size_t)(row0 + ty + TY * r);
        float v0 = acc[r][0] + bb.x;
        float v1 = acc[r][1] + bb.y;
        float v2 = acc[r][2] + bb.z;
        float v3 = acc[r][3] + bb.w;
        if (ACT == 0) {
            v0 = fmaxf(v0, 0.0f); v1 = fmaxf(v1, 0.0f);
            v2 = fmaxf(v2, 0.0f); v3 = fmaxf(v3, 0.0f);
        } else {
            v0 = 1.0f / (1.0f + __expf(-v0));
            v1 = 1.0f / (1.0f + __expf(-v1));
            v2 = 1.0f / (1.0f + __expf(-v2));
            v3 = 1.0f / (1.0f + __expf(-v3));
        }
        typedef __attribute__((ext_vector_type(4))) _Float16 half4;
        half4 hv;
        hv[0] = (_Float16)v0; hv[1] = (_Float16)v1;
        hv[2] = (_Float16)v2; hv[3] = (_Float16)v3;
        *(half4*)(out + nrow * NOUT + j0) = hv;
    }
}

extern "C" void kernel_launch(void* const* d_in, const int* in_sizes, int n_in,
                              void* d_out, int out_size, void* d_ws, size_t ws_size,
                              hipStream_t stream) {
    const float* x     = (const float*)d_in[0];
    const int*   ei    = (const int*)d_in[1];
    // d_in[2]: batch (unused)
    const float* W_lin = (const float*)d_in[3];
    const float* b_lin = (const float*)d_in[4];
    const float* Ws3   = (const float*)d_in[5];
    const float* Wn3   = (const float*)d_in[6];
    const float* b3    = (const float*)d_in[7];
    const float* Ws2   = (const float*)d_in[8];
    const float* Wn2   = (const float*)d_in[9];
    const float* b2    = (const float*)d_in[10];
    const float* Ws1   = (const float*)d_in[11];
    const float* Wn1   = (const float*)d_in[12];
    const float* b1    = (const float*)d_in[13];
    float* out = (float*)d_out;

    const int N = in_sizes[0] / 16;
    const int E = in_sizes[1] / 2;
    const int* src = ei;
    const int* dst = ei + E;
    const int NB = (N + 255) / 256;   // scan blocks (512 for N=131072)

    // Workspace. int section as before; h/agg tables now fp16 (halved).
    //   row_ptr : [0, N+1) ints
    //   cnt     : [N+1, 2N+1) ints
    //   bsum    : [2N+1, 2N+1+NB) ints
    //   csr_src : [A, A+E) ints
    //   rank    : [A+E, A+2E) ints      (CSR build only)
    //   halves at H0 (16B aligned):
    //     regionA (64N halves): h0 [0,16N) agg16 [16N,32N); later h2 [0,64N)
    //     regionB (64N halves): h3 [0,32N) agg32 [32N,64N); later agg64 [0,64N)
    int* wsi = (int*)d_ws;
    int* row_ptr = wsi;
    int* cnt     = wsi + (N + 1);
    int* bsum    = wsi + (2 * N + 1);
    size_t A = (size_t)(2 * N + 1 + NB + 3) & ~(size_t)3;
    int* csr_src = wsi + A;
    int* rank    = wsi + A + (size_t)E;
    size_t H0 = (A + 2 * (size_t)E + 3) & ~(size_t)3;   // int offset, 16B aligned
    _Float16* regA = (_Float16*)(wsi + H0);
    _Float16* regB = regA + (size_t)64 * N;

    _Float16* h0    = regA;
    _Float16* agg16 = regA + (size_t)16 * N;
    _Float16* h2    = regA;                    // after h0/agg16 dead
    _Float16* h3    = regB;
    _Float16* agg32 = regB + (size_t)32 * N;
    _Float16* agg64 = regB;                    // after h3/agg32 dead

    const int BLK = 256;

    // ---- CSR build: hist computes rank; fill is atomic-free ----
    hipMemsetAsync(cnt, 0, (size_t)N * 4, stream);
    hist_rank_kernel<<<(E + BLK - 1) / BLK, BLK, 0, stream>>>(dst, cnt, rank, E);
    scan1_kernel<<<NB, 256, 0, stream>>>(cnt, row_ptr, bsum);
    scan2_kernel<<<1, NB, NB * sizeof(int), stream>>>(bsum, NB);
    scan3_kernel<<<NB, 256, 0, stream>>>(row_ptr, bsum, N, E);
    fill_kernel<<<(E + BLK - 1) / BLK, BLK, 0, stream>>>(src, dst, row_ptr, rank, csr_src, E);

    // ---- h0 = x @ W_lin + b_lin (fp16 out) ----
    lin16_kernel<<<(N + BLK - 1) / BLK, BLK, 0, stream>>>(x, W_lin, b_lin, h0, N);

    // ---- block3: 16 -> 32, relu ----  (gather GP=2)
    gather_kernel<16><<<((size_t)N * 2 + BLK - 1) / BLK, BLK, 0, stream>>>(row_ptr, csr_src, h0, agg16, N);
    gemm_h_kernel<16, 32, 4, 4, 0><<<N / 128, 256, 0, stream>>>(h0, agg16, Ws3, Wn3, b3, h3, N);

    // ---- block2: 32 -> 64, relu ----  (gather GP=4)
    gather_kernel<32><<<((size_t)N * 4 + BLK - 1) / BLK, BLK, 0, stream>>>(row_ptr, csr_src, h3, agg32, N);
    gemm_h_kernel<32, 64, 8, 4, 0><<<N / 128, 256, 0, stream>>>(h3, agg32, Ws2, Wn2, b2, h2, N);

    // ---- block1: 64 -> 128, sigmoid -> d_out (fp32) ----  (gather GP=8)
    gather_kernel<64><<<((size_t)N * 8 + BLK - 1) / BLK, BLK, 0, stream>>>(row_ptr, csr_src, h2, agg64, N);
    gemm_kernel<64, 128, 8, 4, 1><<<N / 64, 256, 0, stream>>>(h2, agg64, Ws1, Wn1, b1, out, N);
}

// Round 9
// 377.435 us; speedup vs baseline: 1.5537x; 1.1768x over previous
//
#include <hip/hip_runtime.h>
#include <cmath>

// ---------------------------------------------------------------------------
// Decoder_1898375544952: STGCN decoder (radix CSR build + fp16 gather + GEMM)
//   h0 = x @ W_lin + b_lin                         [N,16]
//   h3 = relu(h0 @ Ws3 + mean_agg(h0) @ Wn3 + b3)  [N,32]
//   h2 = relu(h3 @ Ws2 + mean_agg(h3) @ Wn2 + b2)  [N,64]
//   out= sigm(h2 @ Ws1 + mean_agg(h2) @ Wn1 + b1)  [N,128]
//
// R1: fp32 atomic scatter = 2 GB HBM write-through -> CSR gather (4.7x).
// R2: combine LDS-BW bound -> register-blocked GEMM.
// R3: over-unrolled GEMM spilled -> unroll-1 chunks, TMx4 tiles.
// R4/R5: CSR fill atomics -> rank-from-hist; R8: fp16 h/agg tables (444us).
// R9: hist_rank(88us)+fill(~70us) = 2M device-scope atomics @ ~25G/s wall ->
//   radix CSR build with LDS atomics ONLY:
//     A bucket_hist: per-block LDS hist over 512 dst-buckets (256 nodes each)
//     B scan of 512x512 (bucket-major) counts -> segment bases
//     C partition: LDS cursors scatter (src,dst) into contiguous segments
//     D local_csr: per-bucket LDS hist+scan -> row_ptr + csr_src (L2-local)
// ---------------------------------------------------------------------------

typedef __attribute__((ext_vector_type(8))) _Float16 half8;

#define NBUCKET 512
#define BUCKET_SHIFT 8   // 256 nodes per bucket; N = 131072 = 512*256

// ---- Pass A: per-block bucket histogram (LDS atomics only) ----
__global__ __launch_bounds__(256) void bucket_hist_kernel(
    const int* __restrict__ dst, int* __restrict__ bcnt, int E, int EPB, int nblk) {
    __shared__ int lh[NBUCKET];
    for (int i = threadIdx.x; i < NBUCKET; i += 256) lh[i] = 0;
    __syncthreads();
    int base = blockIdx.x * EPB;
    int end  = min(base + EPB, E);
    for (int i = base + threadIdx.x; i < end; i += 256)
        atomicAdd(&lh[dst[i] >> BUCKET_SHIFT], 1);
    __syncthreads();
    for (int i = threadIdx.x; i < NBUCKET; i += 256)
        bcnt[i * nblk + blockIdx.x] = lh[i];        // bucket-major
}

// ---- scan helpers (exclusive scan over M = multiple of 256 elements) ----
__global__ void scan1_kernel(const int* __restrict__ in, int* __restrict__ out,
                             int* __restrict__ bsum) {
    __shared__ int s[256];
    int i = blockIdx.x * 256 + threadIdx.x;
    int v = in[i];
    s[threadIdx.x] = v;
    __syncthreads();
    for (int off = 1; off < 256; off <<= 1) {
        int t = (threadIdx.x >= off) ? s[threadIdx.x - off] : 0;
        __syncthreads();
        s[threadIdx.x] += t;
        __syncthreads();
    }
    out[i] = s[threadIdx.x] - v;
    if (threadIdx.x == 255) bsum[blockIdx.x] = s[255];
}

__global__ void scan2_kernel(int* __restrict__ bsum, int NB) {
    extern __shared__ int s2[];
    int v = (threadIdx.x < NB) ? bsum[threadIdx.x] : 0;
    s2[threadIdx.x] = v;
    __syncthreads();
    for (int off = 1; off < NB; off <<= 1) {
        int t = (threadIdx.x >= off) ? s2[threadIdx.x - off] : 0;
        __syncthreads();
        s2[threadIdx.x] += t;
        __syncthreads();
    }
    if (threadIdx.x < NB) bsum[threadIdx.x] = s2[threadIdx.x] - v;
}

__global__ void scan3_kernel(int* __restrict__ out, const int* __restrict__ bsum) {
    int i = blockIdx.x * 256 + threadIdx.x;
    out[i] += bsum[blockIdx.x];
}

// ---- Pass C: partition edges into bucket segments (LDS cursors) ----
__global__ __launch_bounds__(256) void partition_kernel(
    const int* __restrict__ src, const int* __restrict__ dst,
    const int* __restrict__ bofs, int2* __restrict__ part,
    int E, int EPB, int nblk) {
    __shared__ int cur[NBUCKET];
    for (int i = threadIdx.x; i < NBUCKET; i += 256)
        cur[i] = bofs[i * nblk + blockIdx.x];
    __syncthreads();
    int base = blockIdx.x * EPB;
    int end  = min(base + EPB, E);
    for (int i = base + threadIdx.x; i < end; i += 256) {
        int d = dst[i];
        int p = atomicAdd(&cur[d >> BUCKET_SHIFT], 1);
        part[p] = make_int2(src[i], d);
    }
}

// ---- Pass D: per-bucket local CSR (row_ptr + csr_src), all LDS-local ----
__global__ __launch_bounds__(256) void local_csr_kernel(
    const int* __restrict__ bofs, const int2* __restrict__ part,
    int* __restrict__ row_ptr, int* __restrict__ csr_src,
    int N, int E, int nblk) {
    __shared__ int cnt[256];
    __shared__ int offs[256];
    const int u      = blockIdx.x;
    const int node0  = u << BUCKET_SHIFT;
    const int bstart = bofs[(size_t)u * nblk];
    const int bend   = (u + 1 < gridDim.x) ? bofs[(size_t)(u + 1) * nblk] : E;

    cnt[threadIdx.x] = 0;
    __syncthreads();
    for (int i = bstart + threadIdx.x; i < bend; i += 256)
        atomicAdd(&cnt[part[i].y - node0], 1);
    __syncthreads();

    // exclusive scan of cnt -> offs
    int v = cnt[threadIdx.x];
    offs[threadIdx.x] = v;
    __syncthreads();
    for (int off = 1; off < 256; off <<= 1) {
        int t = (threadIdx.x >= off) ? offs[threadIdx.x - off] : 0;
        __syncthreads();
        offs[threadIdx.x] += t;
        __syncthreads();
    }
    int excl = offs[threadIdx.x] - v;
    int rbase = bstart + excl;
    if (node0 + threadIdx.x < N) row_ptr[node0 + threadIdx.x] = rbase;
    if (u == 0 && threadIdx.x == 0) row_ptr[N] = E;
    __syncthreads();
    cnt[threadIdx.x] = rbase;       // reuse as cursor
    __syncthreads();
    for (int i = bstart + threadIdx.x; i < bend; i += 256) {
        int2 e = part[i];
        int p = atomicAdd(&cnt[e.y - node0], 1);
        csr_src[p] = e.x;
    }
}

// h0 = x @ W (16x16) + b, stored fp16
__global__ void lin16_kernel(const float* __restrict__ x, const float* __restrict__ W,
                             const float* __restrict__ b, _Float16* __restrict__ h, int N) {
    __shared__ float sW[256];
    __shared__ float sb[16];
    sW[threadIdx.x] = W[threadIdx.x];          // blockDim.x == 256
    if (threadIdx.x < 16) sb[threadIdx.x] = b[threadIdx.x];
    __syncthreads();
    int n = blockIdx.x * blockDim.x + threadIdx.x;
    if (n >= N) return;
    const float4* xr = (const float4*)(x + (size_t)n * 16);
    float4 x0 = xr[0], x1 = xr[1], x2 = xr[2], x3 = xr[3];
    float xi[16] = {x0.x, x0.y, x0.z, x0.w, x1.x, x1.y, x1.z, x1.w,
                    x2.x, x2.y, x2.z, x2.w, x3.x, x3.y, x3.z, x3.w};
    float o[16];
#pragma unroll
    for (int j = 0; j < 16; j++) o[j] = sb[j];
#pragma unroll
    for (int k = 0; k < 16; k++) {
        float xv = xi[k];
#pragma unroll
        for (int j = 0; j < 16; j++) o[j] += xv * sW[k * 16 + j];
    }
    half8 h0v, h1v;
#pragma unroll
    for (int j = 0; j < 8; j++) { h0v[j] = (_Float16)o[j]; h1v[j] = (_Float16)o[j + 8]; }
    half8* hr = (half8*)(h + (size_t)n * 16);
    hr[0] = h0v;
    hr[1] = h1v;
}

// agg[n][g*8..] = (1/max(deg,1)) * sum over CSR neighbors of h[src][g*8..]
// fp16 storage, fp32 accumulate; 16 B/lane loads; 4-way unrolled.
template <int C>
__global__ void gather_kernel(const int* __restrict__ row_ptr, const int* __restrict__ csr_src,
                              const _Float16* __restrict__ h, _Float16* __restrict__ agg, int N) {
    constexpr int GP = C / 8;
    int t = blockIdx.x * blockDim.x + threadIdx.x;
    int total = N * GP;
    if (t >= total) return;
    int n = t / GP;
    int g = t - n * GP;
    const int beg = row_ptr[n];
    const int end = row_ptr[n + 1];
    const size_t goff = (size_t)g * 8;

    float a0[8], a1[8];
#pragma unroll
    for (int i = 0; i < 8; i++) { a0[i] = 0.f; a1[i] = 0.f; }

    int j = beg;
    for (; j + 4 <= end; j += 4) {
        int i0 = csr_src[j + 0], i1 = csr_src[j + 1], i2 = csr_src[j + 2], i3 = csr_src[j + 3];
        half8 v0 = *(const half8*)(h + (size_t)i0 * C + goff);
        half8 v1 = *(const half8*)(h + (size_t)i1 * C + goff);
        half8 v2 = *(const half8*)(h + (size_t)i2 * C + goff);
        half8 v3 = *(const half8*)(h + (size_t)i3 * C + goff);
#pragma unroll
        for (int i = 0; i < 8; i++) {
            a0[i] += (float)v0[i] + (float)v2[i];
            a1[i] += (float)v1[i] + (float)v3[i];
        }
    }
    for (; j < end; ++j) {
        int i0 = csr_src[j];
        half8 v0 = *(const half8*)(h + (size_t)i0 * C + goff);
#pragma unroll
        for (int i = 0; i < 8; i++) a0[i] += (float)v0[i];
    }

    float inv = 1.0f / fmaxf((float)(end - beg), 1.0f);
    half8 r;
#pragma unroll
    for (int i = 0; i < 8; i++) r[i] = (_Float16)((a0[i] + a1[i]) * inv);
    *(half8*)(agg + (size_t)n * C + goff) = r;
}

// Register-blocked GEMM: out = act([h | a] @ [Ws; Wn] + b). fp32 output.
template <int CI, int NOUT, int TM, int TN, int ACT>
__global__ __launch_bounds__(256) void gemm_kernel(
    const _Float16* __restrict__ hbuf, const _Float16* __restrict__ abuf,
    const float* __restrict__ Ws, const float* __restrict__ Wn,
    const float* __restrict__ bias, float* __restrict__ out, int N)
{
    constexpr int K   = 2 * CI;
    constexpr int BK  = (CI < 32) ? CI : 32;
    constexpr int KQ8 = BK / 8;
    constexpr int TX  = NOUT / TN;
    constexpr int TY  = 256 / TX;
    constexpr int BM  = TY * TM;
    constexpr int LDA = BK + 8;
    __shared__ float As[BM][LDA];
    __shared__ float Bs[BK][NOUT];

    const int tid  = threadIdx.x;
    const int tx   = tid % TX;
    const int ty   = tid / TX;
    const int row0 = blockIdx.x * BM;
    const int j0   = tx * TN;

    float acc[TM][TN];
#pragma unroll
    for (int r = 0; r < TM; r++)
#pragma unroll
        for (int j = 0; j < TN; j++) acc[r][j] = 0.0f;

#pragma unroll 1
    for (int k0 = 0; k0 < K; k0 += BK) {
        const _Float16* Asrc;
        const float* Bsrc;
        int ks;
        if (k0 < CI) { Asrc = hbuf; Bsrc = Ws; ks = k0; }
        else         { Asrc = abuf; Bsrc = Wn; ks = k0 - CI; }

        for (int idx = tid; idx < BM * KQ8; idx += 256) {
            int m  = idx / KQ8;
            int kq = idx - m * KQ8;
            half8 v = *(const half8*)(Asrc + (size_t)(row0 + m) * CI + ks + kq * 8);
            float4 f0, f1;
            f0.x = (float)v[0]; f0.y = (float)v[1]; f0.z = (float)v[2]; f0.w = (float)v[3];
            f1.x = (float)v[4]; f1.y = (float)v[5]; f1.z = (float)v[6]; f1.w = (float)v[7];
            *(float4*)&As[m][kq * 8]     = f0;
            *(float4*)&As[m][kq * 8 + 4] = f1;
        }
        for (int idx = tid; idx < BK * (NOUT / 4); idx += 256) {
            int kk = idx / (NOUT / 4);
            int jq = idx - kk * (NOUT / 4);
            *(float4*)&Bs[kk][jq * 4] =
                *(const float4*)(Bsrc + (size_t)(ks + kk) * NOUT + jq * 4);
        }
        __syncthreads();

#pragma unroll 8
        for (int k = 0; k < BK; k++) {
            float4 bv = *(const float4*)&Bs[k][j0];
            float a[TM];
#pragma unroll
            for (int r = 0; r < TM; r++) a[r] = As[ty + TY * r][k];
#pragma unroll
            for (int r = 0; r < TM; r++) {
                acc[r][0] += a[r] * bv.x;
                acc[r][1] += a[r] * bv.y;
                acc[r][2] += a[r] * bv.z;
                acc[r][3] += a[r] * bv.w;
            }
        }
        __syncthreads();
    }

    float4 bb = *(const float4*)(bias + j0);
#pragma unroll
    for (int r = 0; r < TM; r++) {
        size_t nrow = (size_t)(row0 + ty + TY * r);
        float4 v;
        v.x = acc[r][0] + bb.x;
        v.y = acc[r][1] + bb.y;
        v.z = acc[r][2] + bb.z;
        v.w = acc[r][3] + bb.w;
        if (ACT == 0) {
            v.x = fmaxf(v.x, 0.0f); v.y = fmaxf(v.y, 0.0f);
            v.z = fmaxf(v.z, 0.0f); v.w = fmaxf(v.w, 0.0f);
        } else {
            v.x = 1.0f / (1.0f + __expf(-v.x));
            v.y = 1.0f / (1.0f + __expf(-v.y));
            v.z = 1.0f / (1.0f + __expf(-v.z));
            v.w = 1.0f / (1.0f + __expf(-v.w));
        }
        *(float4*)(out + nrow * NOUT + j0) = v;
    }
}

// Variant writing fp16 output (intermediate layers).
template <int CI, int NOUT, int TM, int TN, int ACT>
__global__ __launch_bounds__(256) void gemm_h_kernel(
    const _Float16* __restrict__ hbuf, const _Float16* __restrict__ abuf,
    const float* __restrict__ Ws, const float* __restrict__ Wn,
    const float* __restrict__ bias, _Float16* __restrict__ out, int N)
{
    constexpr int K   = 2 * CI;
    constexpr int BK  = (CI < 32) ? CI : 32;
    constexpr int KQ8 = BK / 8;
    constexpr int TX  = NOUT / TN;
    constexpr int TY  = 256 / TX;
    constexpr int BM  = TY * TM;
    constexpr int LDA = BK + 8;
    __shared__ float As[BM][LDA];
    __shared__ float Bs[BK][NOUT];

    const int tid  = threadIdx.x;
    const int tx   = tid % TX;
    const int ty   = tid / TX;
    const int row0 = blockIdx.x * BM;
    const int j0   = tx * TN;

    float acc[TM][TN];
#pragma unroll
    for (int r = 0; r < TM; r++)
#pragma unroll
        for (int j = 0; j < TN; j++) acc[r][j] = 0.0f;

#pragma unroll 1
    for (int k0 = 0; k0 < K; k0 += BK) {
        const _Float16* Asrc;
        const float* Bsrc;
        int ks;
        if (k0 < CI) { Asrc = hbuf; Bsrc = Ws; ks = k0; }
        else         { Asrc = abuf; Bsrc = Wn; ks = k0 - CI; }

        for (int idx = tid; idx < BM * KQ8; idx += 256) {
            int m  = idx / KQ8;
            int kq = idx - m * KQ8;
            half8 v = *(const half8*)(Asrc + (size_t)(row0 + m) * CI + ks + kq * 8);
            float4 f0, f1;
            f0.x = (float)v[0]; f0.y = (float)v[1]; f0.z = (float)v[2]; f0.w = (float)v[3];
            f1.x = (float)v[4]; f1.y = (float)v[5]; f1.z = (float)v[6]; f1.w = (float)v[7];
            *(float4*)&As[m][kq * 8]     = f0;
            *(float4*)&As[m][kq * 8 + 4] = f1;
        }
        for (int idx = tid; idx < BK * (NOUT / 4); idx += 256) {
            int kk = idx / (NOUT / 4);
            int jq = idx - kk * (NOUT / 4);
            *(float4*)&Bs[kk][jq * 4] =
                *(const float4*)(Bsrc + (size_t)(ks + kk) * NOUT + jq * 4);
        }
        __syncthreads();

#pragma unroll 8
        for (int k = 0; k < BK; k++) {
            float4 bv = *(const float4*)&Bs[k][j0];
            float a[TM];
#pragma unroll
            for (int r = 0; r < TM; r++) a[r] = As[ty + TY * r][k];
#pragma unroll
            for (int r = 0; r < TM; r++) {
                acc[r][0] += a[r] * bv.x;
                acc[r][1] += a[r] * bv.y;
                acc[r][2] += a[r] * bv.z;
                acc[r][3] += a[r] * bv.w;
            }
        }
        __syncthreads();
    }

    float4 bb = *(const float4*)(bias + j0);
#pragma unroll
    for (int r = 0; r < TM; r++) {
        size_t nrow = (size_t)(row0 + ty + TY * r);
        float v0 = acc[r][0] + bb.x;
        float v1 = acc[r][1] + bb.y;
        float v2 = acc[r][2] + bb.z;
        float v3 = acc[r][3] + bb.w;
        if (ACT == 0) {
            v0 = fmaxf(v0, 0.0f); v1 = fmaxf(v1, 0.0f);
            v2 = fmaxf(v2, 0.0f); v3 = fmaxf(v3, 0.0f);
        } else {
            v0 = 1.0f / (1.0f + __expf(-v0));
            v1 = 1.0f / (1.0f + __expf(-v1));
            v2 = 1.0f / (1.0f + __expf(-v2));
            v3 = 1.0f / (1.0f + __expf(-v3));
        }
        typedef __attribute__((ext_vector_type(4))) _Float16 half4;
        half4 hv;
        hv[0] = (_Float16)v0; hv[1] = (_Float16)v1;
        hv[2] = (_Float16)v2; hv[3] = (_Float16)v3;
        *(half4*)(out + nrow * NOUT + j0) = hv;
    }
}

extern "C" void kernel_launch(void* const* d_in, const int* in_sizes, int n_in,
                              void* d_out, int out_size, void* d_ws, size_t ws_size,
                              hipStream_t stream) {
    const float* x     = (const float*)d_in[0];
    const int*   ei    = (const int*)d_in[1];
    // d_in[2]: batch (unused)
    const float* W_lin = (const float*)d_in[3];
    const float* b_lin = (const float*)d_in[4];
    const float* Ws3   = (const float*)d_in[5];
    const float* Wn3   = (const float*)d_in[6];
    const float* b3    = (const float*)d_in[7];
    const float* Ws2   = (const float*)d_in[8];
    const float* Wn2   = (const float*)d_in[9];
    const float* b2    = (const float*)d_in[10];
    const float* Ws1   = (const float*)d_in[11];
    const float* Wn1   = (const float*)d_in[12];
    const float* b1    = (const float*)d_in[13];
    float* out = (float*)d_out;

    const int N = in_sizes[0] / 16;
    const int E = in_sizes[1] / 2;
    const int* src = ei;
    const int* dst = ei + E;

    const int NBLK = 512;                       // partition blocks
    const int EPB  = (E + NBLK - 1) / NBLK;     // 4096 for E=2M
    const int M    = NBUCKET * NBLK;            // 262144 count entries
    const int NB2  = M / 256;                   // 1024 scan blocks

    // Workspace (ints unless noted). ~51 MB total.
    //   row_ptr : [0, N+1)
    //   bcnt    : [B0, B0+M)
    //   bofs    : [B0+M, B0+2M)
    //   bsum    : [B0+2M, B0+2M+NB2)
    //   csr_src : [C0, C0+E)
    //   part    : [P0, P0+2E)  int2, 8B aligned
    //   halves at H0: regA 64N halves; regB 64N halves
    int* wsi = (int*)d_ws;
    int* row_ptr = wsi;
    size_t B0 = ((size_t)(N + 1) + 3) & ~(size_t)3;
    int* bcnt = wsi + B0;
    int* bofs = bcnt + M;
    int* bsum = bofs + M;
    size_t C0 = (B0 + 2 * (size_t)M + (size_t)NB2 + 3) & ~(size_t)3;
    int* csr_src = wsi + C0;
    size_t P0 = (C0 + (size_t)E + 3) & ~(size_t)3;
    int2* part = (int2*)(wsi + P0);
    size_t H0 = (P0 + 2 * (size_t)E + 3) & ~(size_t)3;
    _Float16* regA = (_Float16*)(wsi + H0);
    _Float16* regB = regA + (size_t)64 * N;

    _Float16* h0    = regA;
    _Float16* agg16 = regA + (size_t)16 * N;
    _Float16* h2    = regA;                    // after h0/agg16 dead
    _Float16* h3    = regB;
    _Float16* agg32 = regB + (size_t)32 * N;
    _Float16* agg64 = regB;                    // after h3/agg32 dead

    const int BLK = 256;

    // ---- radix CSR build: zero global atomics ----
    bucket_hist_kernel<<<NBLK, 256, 0, stream>>>(dst, bcnt, E, EPB, NBLK);
    scan1_kernel<<<NB2, 256, 0, stream>>>(bcnt, bofs, bsum);
    scan2_kernel<<<1, NB2, NB2 * sizeof(int), stream>>>(bsum, NB2);
    scan3_kernel<<<NB2, 256, 0, stream>>>(bofs, bsum);
    partition_kernel<<<NBLK, 256, 0, stream>>>(src, dst, bofs, part, E, EPB, NBLK);
    local_csr_kernel<<<NBUCKET, 256, 0, stream>>>(bofs, part, row_ptr, csr_src, N, E, NBLK);

    // ---- h0 = x @ W_lin + b_lin (fp16 out) ----
    lin16_kernel<<<(N + BLK - 1) / BLK, BLK, 0, stream>>>(x, W_lin, b_lin, h0, N);

    // ---- block3: 16 -> 32, relu ----
    gather_kernel<16><<<((size_t)N * 2 + BLK - 1) / BLK, BLK, 0, stream>>>(row_ptr, csr_src, h0, agg16, N);
    gemm_h_kernel<16, 32, 4, 4, 0><<<N / 128, 256, 0, stream>>>(h0, agg16, Ws3, Wn3, b3, h3, N);

    // ---- block2: 32 -> 64, relu ----
    gather_kernel<32><<<((size_t)N * 4 + BLK - 1) / BLK, BLK, 0, stream>>>(row_ptr, csr_src, h3, agg32, N);
    gemm_h_kernel<32, 64, 8, 4, 0><<<N / 128, 256, 0, stream>>>(h3, agg32, Ws2, Wn2, b2, h2, N);

    // ---- block1: 64 -> 128, sigmoid -> d_out (fp32) ----
    gather_kernel<64><<<((size_t)N * 8 + BLK - 1) / BLK, BLK, 0, stream>>>(row_ptr, csr_src, h2, agg64, N);
    gemm_kernel<64, 128, 8, 4, 1><<<N / 64, 256, 0, stream>>>(h2, agg64, Ws1, Wn1, b1, out, N);
}

// Round 10
// 334.734 us; speedup vs baseline: 1.7519x; 1.1276x over previous
//
#include <hip/hip_runtime.h>
#include <cmath>

// ---------------------------------------------------------------------------
// Decoder_1898375544952: STGCN decoder (radix CSR + fp16 gather + MFMA GEMM)
//   h0 = x @ W_lin + b_lin                         [N,16]
//   h3 = relu(h0 @ Ws3 + mean_agg(h0) @ Wn3 + b3)  [N,32]
//   h2 = relu(h3 @ Ws2 + mean_agg(h3) @ Wn2 + b2)  [N,64]
//   out= sigm(h2 @ Ws1 + mean_agg(h2) @ Wn1 + b1)  [N,128]
//
// R1: atomic scatter -> CSR gather. R2: reg-blocked GEMM. R3: spill fix.
// R4/R5: atomic-free fill. R8: fp16 h/agg tables. R9: radix CSR build
//   (LDS atomics only) -> 377us.
// R10: vector GEMMs (73us layer-1, issue-floor 27us) -> fp16 MFMA
//   (mfma_f32_16x16x32_f16, ~2.5PF pipe). Wt = [Ws;Wn]^T pre-transposed to
//   fp16 [NOUT][K]; A-frag half8 direct from h/agg (A[m=lane&15][k=quad*8+j],
//   8|CI so each frag is within one half); B-frag half8 from padded LDS
//   (stride K+8 halves -> <=2-way banks, free); C/D col=lane&15,row=quad*4+reg.
// ---------------------------------------------------------------------------

typedef __attribute__((ext_vector_type(8))) _Float16 half8;
typedef __attribute__((ext_vector_type(4))) float floatx4;

#define NBUCKET 512
#define BUCKET_SHIFT 8   // 256 nodes per bucket; N = 131072 = 512*256

// ---- Pass A: per-block bucket histogram (LDS atomics only) ----
__global__ __launch_bounds__(256) void bucket_hist_kernel(
    const int* __restrict__ dst, int* __restrict__ bcnt, int E, int EPB, int nblk) {
    __shared__ int lh[NBUCKET];
    for (int i = threadIdx.x; i < NBUCKET; i += 256) lh[i] = 0;
    __syncthreads();
    int base = blockIdx.x * EPB;
    int end  = min(base + EPB, E);
    for (int i = base + threadIdx.x; i < end; i += 256)
        atomicAdd(&lh[dst[i] >> BUCKET_SHIFT], 1);
    __syncthreads();
    for (int i = threadIdx.x; i < NBUCKET; i += 256)
        bcnt[i * nblk + blockIdx.x] = lh[i];        // bucket-major
}

// ---- scan helpers ----
__global__ void scan1_kernel(const int* __restrict__ in, int* __restrict__ out,
                             int* __restrict__ bsum) {
    __shared__ int s[256];
    int i = blockIdx.x * 256 + threadIdx.x;
    int v = in[i];
    s[threadIdx.x] = v;
    __syncthreads();
    for (int off = 1; off < 256; off <<= 1) {
        int t = (threadIdx.x >= off) ? s[threadIdx.x - off] : 0;
        __syncthreads();
        s[threadIdx.x] += t;
        __syncthreads();
    }
    out[i] = s[threadIdx.x] - v;
    if (threadIdx.x == 255) bsum[blockIdx.x] = s[255];
}

__global__ void scan2_kernel(int* __restrict__ bsum, int NB) {
    extern __shared__ int s2[];
    int v = (threadIdx.x < NB) ? bsum[threadIdx.x] : 0;
    s2[threadIdx.x] = v;
    __syncthreads();
    for (int off = 1; off < NB; off <<= 1) {
        int t = (threadIdx.x >= off) ? s2[threadIdx.x - off] : 0;
        __syncthreads();
        s2[threadIdx.x] += t;
        __syncthreads();
    }
    if (threadIdx.x < NB) bsum[threadIdx.x] = s2[threadIdx.x] - v;
}

__global__ void scan3_kernel(int* __restrict__ out, const int* __restrict__ bsum) {
    int i = blockIdx.x * 256 + threadIdx.x;
    out[i] += bsum[blockIdx.x];
}

// ---- Pass C: partition edges into bucket segments (LDS cursors) ----
__global__ __launch_bounds__(256) void partition_kernel(
    const int* __restrict__ src, const int* __restrict__ dst,
    const int* __restrict__ bofs, int2* __restrict__ part,
    int E, int EPB, int nblk) {
    __shared__ int cur[NBUCKET];
    for (int i = threadIdx.x; i < NBUCKET; i += 256)
        cur[i] = bofs[i * nblk + blockIdx.x];
    __syncthreads();
    int base = blockIdx.x * EPB;
    int end  = min(base + EPB, E);
    for (int i = base + threadIdx.x; i < end; i += 256) {
        int d = dst[i];
        int p = atomicAdd(&cur[d >> BUCKET_SHIFT], 1);
        part[p] = make_int2(src[i], d);
    }
}

// ---- Pass D: per-bucket local CSR (row_ptr + csr_src), all LDS-local ----
__global__ __launch_bounds__(256) void local_csr_kernel(
    const int* __restrict__ bofs, const int2* __restrict__ part,
    int* __restrict__ row_ptr, int* __restrict__ csr_src,
    int N, int E, int nblk) {
    __shared__ int cnt[256];
    __shared__ int offs[256];
    const int u      = blockIdx.x;
    const int node0  = u << BUCKET_SHIFT;
    const int bstart = bofs[(size_t)u * nblk];
    const int bend   = (u + 1 < gridDim.x) ? bofs[(size_t)(u + 1) * nblk] : E;

    cnt[threadIdx.x] = 0;
    __syncthreads();
    for (int i = bstart + threadIdx.x; i < bend; i += 256)
        atomicAdd(&cnt[part[i].y - node0], 1);
    __syncthreads();

    int v = cnt[threadIdx.x];
    offs[threadIdx.x] = v;
    __syncthreads();
    for (int off = 1; off < 256; off <<= 1) {
        int t = (threadIdx.x >= off) ? offs[threadIdx.x - off] : 0;
        __syncthreads();
        offs[threadIdx.x] += t;
        __syncthreads();
    }
    int excl = offs[threadIdx.x] - v;
    int rbase = bstart + excl;
    if (node0 + threadIdx.x < N) row_ptr[node0 + threadIdx.x] = rbase;
    if (u == 0 && threadIdx.x == 0) row_ptr[N] = E;
    __syncthreads();
    cnt[threadIdx.x] = rbase;       // reuse as cursor
    __syncthreads();
    for (int i = bstart + threadIdx.x; i < bend; i += 256) {
        int2 e = part[i];
        int p = atomicAdd(&cnt[e.y - node0], 1);
        csr_src[p] = e.x;
    }
}

// ---- weight transpose+concat: Wt[n][k] = (k<CI ? Ws[k][n] : Wn[k-CI][n]) fp16
__global__ void wt_kernel(const float* __restrict__ Ws, const float* __restrict__ Wn,
                          _Float16* __restrict__ Wt, int CI, int NOUT) {
    int K = 2 * CI;
    int idx = blockIdx.x * 256 + threadIdx.x;
    if (idx >= NOUT * K) return;
    int n = idx / K, k = idx - n * K;
    float v = (k < CI) ? Ws[(size_t)k * NOUT + n] : Wn[(size_t)(k - CI) * NOUT + n];
    Wt[idx] = (_Float16)v;
}

// h0 = x @ W (16x16) + b, stored fp16
__global__ void lin16_kernel(const float* __restrict__ x, const float* __restrict__ W,
                             const float* __restrict__ b, _Float16* __restrict__ h, int N) {
    __shared__ float sW[256];
    __shared__ float sb[16];
    sW[threadIdx.x] = W[threadIdx.x];          // blockDim.x == 256
    if (threadIdx.x < 16) sb[threadIdx.x] = b[threadIdx.x];
    __syncthreads();
    int n = blockIdx.x * blockDim.x + threadIdx.x;
    if (n >= N) return;
    const float4* xr = (const float4*)(x + (size_t)n * 16);
    float4 x0 = xr[0], x1 = xr[1], x2 = xr[2], x3 = xr[3];
    float xi[16] = {x0.x, x0.y, x0.z, x0.w, x1.x, x1.y, x1.z, x1.w,
                    x2.x, x2.y, x2.z, x2.w, x3.x, x3.y, x3.z, x3.w};
    float o[16];
#pragma unroll
    for (int j = 0; j < 16; j++) o[j] = sb[j];
#pragma unroll
    for (int k = 0; k < 16; k++) {
        float xv = xi[k];
#pragma unroll
        for (int j = 0; j < 16; j++) o[j] += xv * sW[k * 16 + j];
    }
    half8 h0v, h1v;
#pragma unroll
    for (int j = 0; j < 8; j++) { h0v[j] = (_Float16)o[j]; h1v[j] = (_Float16)o[j + 8]; }
    half8* hr = (half8*)(h + (size_t)n * 16);
    hr[0] = h0v;
    hr[1] = h1v;
}

// agg[n][g*8..] = (1/max(deg,1)) * sum over CSR neighbors of h[src][g*8..]
template <int C>
__global__ void gather_kernel(const int* __restrict__ row_ptr, const int* __restrict__ csr_src,
                              const _Float16* __restrict__ h, _Float16* __restrict__ agg, int N) {
    constexpr int GP = C / 8;
    int t = blockIdx.x * blockDim.x + threadIdx.x;
    int total = N * GP;
    if (t >= total) return;
    int n = t / GP;
    int g = t - n * GP;
    const int beg = row_ptr[n];
    const int end = row_ptr[n + 1];
    const size_t goff = (size_t)g * 8;

    float a0[8], a1[8];
#pragma unroll
    for (int i = 0; i < 8; i++) { a0[i] = 0.f; a1[i] = 0.f; }

    int j = beg;
    for (; j + 4 <= end; j += 4) {
        int i0 = csr_src[j + 0], i1 = csr_src[j + 1], i2 = csr_src[j + 2], i3 = csr_src[j + 3];
        half8 v0 = *(const half8*)(h + (size_t)i0 * C + goff);
        half8 v1 = *(const half8*)(h + (size_t)i1 * C + goff);
        half8 v2 = *(const half8*)(h + (size_t)i2 * C + goff);
        half8 v3 = *(const half8*)(h + (size_t)i3 * C + goff);
#pragma unroll
        for (int i = 0; i < 8; i++) {
            a0[i] += (float)v0[i] + (float)v2[i];
            a1[i] += (float)v1[i] + (float)v3[i];
        }
    }
    for (; j < end; ++j) {
        int i0 = csr_src[j];
        half8 v0 = *(const half8*)(h + (size_t)i0 * C + goff);
#pragma unroll
        for (int i = 0; i < 8; i++) a0[i] += (float)v0[i];
    }

    float inv = 1.0f / fmaxf((float)(end - beg), 1.0f);
    half8 r;
#pragma unroll
    for (int i = 0; i < 8; i++) r[i] = (_Float16)((a0[i] + a1[i]) * inv);
    *(half8*)(agg + (size_t)n * C + goff) = r;
}

// ---- MFMA GEMM: out = act([h | a] @ Wt^T + b) with Wt[n][K] fp16 ----
// Block = 256 threads = 4 waves; wave w handles rows blockIdx.x*64 + w*16 .. +16.
// A-frag: lane m=lane&15, quad=lane>>4 reads h/a[row][s*32+quad*8 .. +8].
// B-frag: lane reads Bt[c*16+m][s*32+quad*8 .. +8] from padded LDS.
// C/D: col = c*16 + (lane&15), row = row0 + quad*4 + reg.
// ACT: 0 relu, 1 sigmoid. OUT_F16: fp16 vs fp32 output.
template <int CI, int NOUT, int ACT, bool OUT_F16>
__global__ __launch_bounds__(256) void mfma_gemm_kernel(
    const _Float16* __restrict__ hbuf, const _Float16* __restrict__ abuf,
    const _Float16* __restrict__ Wt,   // [NOUT][K] fp16
    const float* __restrict__ bias, void* __restrict__ outp, int N)
{
    constexpr int K   = 2 * CI;
    constexpr int KS  = K / 32;        // k-steps (4/2/1)
    constexpr int CT  = NOUT / 16;     // col tiles (8/4/2)
    constexpr int LDW = K + 8;         // padded LDS row (halves); LDW*2 % 16 == 0
    __shared__ _Float16 Bt[NOUT * LDW];

    const int tid = threadIdx.x;
    // stage Wt -> LDS (half8 copies)
    for (int idx = tid; idx < NOUT * (K / 8); idx += 256) {
        int n  = idx / (K / 8);
        int kq = idx - n * (K / 8);
        *(half8*)&Bt[n * LDW + kq * 8] = *(const half8*)(Wt + (size_t)n * K + kq * 8);
    }
    __syncthreads();

    const int wave = tid >> 6;
    const int lane = tid & 63;
    const int m    = lane & 15;
    const int quad = lane >> 4;
    const int row0 = blockIdx.x * 64 + wave * 16;
    const size_t row = (size_t)(row0 + m);

    floatx4 acc[CT];
#pragma unroll
    for (int c = 0; c < CT; c++) acc[c] = (floatx4){0.f, 0.f, 0.f, 0.f};

#pragma unroll
    for (int s = 0; s < KS; s++) {
        int k8 = s * 32 + quad * 8;
        const _Float16* Ap = (k8 < CI) ? (hbuf + row * CI + k8)
                                       : (abuf + row * CI + (k8 - CI));
        half8 a = *(const half8*)Ap;
#pragma unroll
        for (int c = 0; c < CT; c++) {
            half8 b = *(const half8*)&Bt[(c * 16 + m) * LDW + k8];
            acc[c] = __builtin_amdgcn_mfma_f32_16x16x32_f16(a, b, acc[c], 0, 0, 0);
        }
    }

    // epilogue
#pragma unroll
    for (int c = 0; c < CT; c++) {
        int col = c * 16 + m;
        float bv = bias[col];
#pragma unroll
        for (int j = 0; j < 4; j++) {
            int orow = row0 + quad * 4 + j;
            float v = acc[c][j] + bv;
            if (ACT == 0) v = fmaxf(v, 0.0f);
            else          v = 1.0f / (1.0f + __expf(-v));
            if (OUT_F16) ((_Float16*)outp)[(size_t)orow * NOUT + col] = (_Float16)v;
            else         ((float*)outp)[(size_t)orow * NOUT + col] = v;
        }
    }
}

extern "C" void kernel_launch(void* const* d_in, const int* in_sizes, int n_in,
                              void* d_out, int out_size, void* d_ws, size_t ws_size,
                              hipStream_t stream) {
    const float* x     = (const float*)d_in[0];
    const int*   ei    = (const int*)d_in[1];
    // d_in[2]: batch (unused)
    const float* W_lin = (const float*)d_in[3];
    const float* b_lin = (const float*)d_in[4];
    const float* Ws3   = (const float*)d_in[5];
    const float* Wn3   = (const float*)d_in[6];
    const float* b3    = (const float*)d_in[7];
    const float* Ws2   = (const float*)d_in[8];
    const float* Wn2   = (const float*)d_in[9];
    const float* b2    = (const float*)d_in[10];
    const float* Ws1   = (const float*)d_in[11];
    const float* Wn1   = (const float*)d_in[12];
    const float* b1    = (const float*)d_in[13];
    float* out = (float*)d_out;

    const int N = in_sizes[0] / 16;
    const int E = in_sizes[1] / 2;
    const int* src = ei;
    const int* dst = ei + E;

    const int NBLK = 512;                       // partition blocks
    const int EPB  = (E + NBLK - 1) / NBLK;
    const int M    = NBUCKET * NBLK;            // 262144 count entries
    const int NB2  = M / 256;

    // Workspace (ints unless noted). ~51 MB total.
    int* wsi = (int*)d_ws;
    int* row_ptr = wsi;
    size_t B0 = ((size_t)(N + 1) + 3) & ~(size_t)3;
    int* bcnt = wsi + B0;
    int* bofs = bcnt + M;
    int* bsum = bofs + M;
    size_t C0 = (B0 + 2 * (size_t)M + (size_t)NB2 + 3) & ~(size_t)3;
    int* csr_src = wsi + C0;
    size_t P0 = (C0 + (size_t)E + 3) & ~(size_t)3;
    int2* part = (int2*)(wsi + P0);
    size_t H0 = (P0 + 2 * (size_t)E + 3) & ~(size_t)3;
    _Float16* regA = (_Float16*)(wsi + H0);
    _Float16* regB = regA + (size_t)64 * N;
    _Float16* Wt1  = regB + (size_t)64 * N;     // 128*128 = 16384 halves
    _Float16* Wt2  = Wt1 + 16384;               // 64*64   = 4096
    _Float16* Wt3  = Wt2 + 4096;                // 32*32   = 1024

    _Float16* h0    = regA;
    _Float16* agg16 = regA + (size_t)16 * N;
    _Float16* h2    = regA;                    // after h0/agg16 dead
    _Float16* h3    = regB;
    _Float16* agg32 = regB + (size_t)32 * N;
    _Float16* agg64 = regB;                    // after h3/agg32 dead

    const int BLK = 256;

    // ---- weight transposes (tiny) ----
    wt_kernel<<<(32 * 32 + 255) / 256, 256, 0, stream>>>(Ws3, Wn3, Wt3, 16, 32);
    wt_kernel<<<(64 * 64 + 255) / 256, 256, 0, stream>>>(Ws2, Wn2, Wt2, 32, 64);
    wt_kernel<<<(128 * 128 + 255) / 256, 256, 0, stream>>>(Ws1, Wn1, Wt1, 64, 128);

    // ---- radix CSR build: zero global atomics ----
    bucket_hist_kernel<<<NBLK, 256, 0, stream>>>(dst, bcnt, E, EPB, NBLK);
    scan1_kernel<<<NB2, 256, 0, stream>>>(bcnt, bofs, bsum);
    scan2_kernel<<<1, NB2, NB2 * sizeof(int), stream>>>(bsum, NB2);
    scan3_kernel<<<NB2, 256, 0, stream>>>(bofs, bsum);
    partition_kernel<<<NBLK, 256, 0, stream>>>(src, dst, bofs, part, E, EPB, NBLK);
    local_csr_kernel<<<NBUCKET, 256, 0, stream>>>(bofs, part, row_ptr, csr_src, N, E, NBLK);

    // ---- h0 = x @ W_lin + b_lin (fp16 out) ----
    lin16_kernel<<<(N + BLK - 1) / BLK, BLK, 0, stream>>>(x, W_lin, b_lin, h0, N);

    // ---- block3: 16 -> 32, relu ----
    gather_kernel<16><<<((size_t)N * 2 + BLK - 1) / BLK, BLK, 0, stream>>>(row_ptr, csr_src, h0, agg16, N);
    mfma_gemm_kernel<16, 32, 0, true><<<N / 64, 256, 0, stream>>>(h0, agg16, Wt3, b3, h3, N);

    // ---- block2: 32 -> 64, relu ----
    gather_kernel<32><<<((size_t)N * 4 + BLK - 1) / BLK, BLK, 0, stream>>>(row_ptr, csr_src, h3, agg32, N);
    mfma_gemm_kernel<32, 64, 0, true><<<N / 64, 256, 0, stream>>>(h3, agg32, Wt2, b2, h2, N);

    // ---- block1: 64 -> 128, sigmoid -> d_out (fp32) ----
    gather_kernel<64><<<((size_t)N * 8 + BLK - 1) / BLK, BLK, 0, stream>>>(row_ptr, csr_src, h2, agg64, N);
    mfma_gemm_kernel<64, 128, 1, false><<<N / 64, 256, 0, stream>>>(h2, agg64, Wt1, b1, out, N);
}